// Round 5
// baseline (244.538 us; speedup 1.0000x reference)
//
#include <hip/hip_runtime.h>

#define NB    131072   // batch rows
#define TPB   128      // 2 waves/block: wave0 = k[0,128), wave1 = k[128,256) + hx tail
#define FANIN 260
#define WL_F4 1044     // Wp (4160 floats = 1040 float4) + bth (16 floats = 4 float4)

__device__ __forceinline__ float sigm_(float x) { return 1.0f / (1.0f + __expf(-x)); }
__device__ __forceinline__ float tanh_(float x) { return 1.0f - 2.0f / (__expf(2.0f * x) + 1.0f); }

// Repack the four [4,260] weight matrices into k-major Wp[k][16] (gw = g*4+w)
// and fuse bias+theta into bth[16] (contiguous after Wp). ws re-poison is
// UNCONDITIONAL (measured r1), so using the workspace costs nothing.
__global__ void qlstm_prep(const float* __restrict__ Wf, const float* __restrict__ bf,
                           const float* __restrict__ Wi, const float* __restrict__ bi,
                           const float* __restrict__ Wu, const float* __restrict__ bu,
                           const float* __restrict__ Wo, const float* __restrict__ bo,
                           const float* __restrict__ thf, const float* __restrict__ thi,
                           const float* __restrict__ thu, const float* __restrict__ tho,
                           float* __restrict__ Wp, float* __restrict__ bth) {
    int t = blockIdx.x * blockDim.x + threadIdx.x;
    if (t < FANIN * 16) {
        int k = t >> 4, gw = t & 15, g = gw >> 2, w = gw & 3;
        const float* Wg = (g == 0) ? Wf : (g == 1) ? Wi : (g == 2) ? Wu : Wo;
        Wp[t] = Wg[w * FANIN + k];
    }
    if (t < 16) {
        int g = t >> 2, w = t & 3;
        const float* bg = (g == 0) ? bf  : (g == 1) ? bi  : (g == 2) ? bu  : bo;
        const float* tg = (g == 0) ? thf : (g == 1) ? thi : (g == 2) ? thu : tho;
        bth[t] = bg[w] + tg[w];
    }
}

// One 32-column chunk: weights via uniform-address ds_read_b128 broadcast
// (same-address LDS access is conflict-free; offsets compile-time after unroll).
__device__ __forceinline__ void consume8(const float4 (&b)[8],
                                         const float4* __restrict__ wst,  // LDS, 128 float4
                                         float (&acc)[16]) {
#pragma unroll
    for (int u = 0; u < 8; ++u) {
#pragma unroll
        for (int m = 0; m < 4; ++m) {
            const int kk = u * 4 + m;
            float xe = (m == 0) ? b[u].x : (m == 1) ? b[u].y
                     : (m == 2) ? b[u].z : b[u].w;
            float4 w0 = wst[kk * 4 + 0], w1 = wst[kk * 4 + 1];
            float4 w2 = wst[kk * 4 + 2], w3 = wst[kk * 4 + 3];
            acc[ 0] = fmaf(xe, w0.x, acc[ 0]); acc[ 1] = fmaf(xe, w0.y, acc[ 1]);
            acc[ 2] = fmaf(xe, w0.z, acc[ 2]); acc[ 3] = fmaf(xe, w0.w, acc[ 3]);
            acc[ 4] = fmaf(xe, w1.x, acc[ 4]); acc[ 5] = fmaf(xe, w1.y, acc[ 5]);
            acc[ 6] = fmaf(xe, w1.z, acc[ 6]); acc[ 7] = fmaf(xe, w1.w, acc[ 7]);
            acc[ 8] = fmaf(xe, w2.x, acc[ 8]); acc[ 9] = fmaf(xe, w2.y, acc[ 9]);
            acc[10] = fmaf(xe, w2.z, acc[10]); acc[11] = fmaf(xe, w2.w, acc[11]);
            acc[12] = fmaf(xe, w3.x, acc[12]); acc[13] = fmaf(xe, w3.y, acc[13]);
            acc[14] = fmaf(xe, w3.z, acc[14]); acc[15] = fmaf(xe, w3.w, acc[15]);
        }
    }
}

__global__ __launch_bounds__(TPB, 3) void qlstm_main(
        const float* __restrict__ x, const float* __restrict__ hx,
        const float* __restrict__ cx, const float* __restrict__ Wp,
        const float* __restrict__ bth, float* __restrict__ out) {
    // Weights+bth in LDS (16704 B). First 4 KB is REUSED after the FMA phase
    // as the cross-wave partial-accumulator exchange buffer (barrier-separated).
    __shared__ float4 wl4[WL_F4];

    const int tid  = threadIdx.x;
    const int lane = tid & 63;
    const int wv   = tid >> 6;
    const int wvu  = __builtin_amdgcn_readfirstlane(wv);
    const int row0 = blockIdx.x * 64;
    const int row  = row0 + lane;

    // One coalesced copy of Wp+bth (contiguous in ws) into LDS per block.
    {
        const float4* wp4 = (const float4*)Wp;
#pragma unroll
        for (int i = 0; i < 9; ++i) {
            int idx = tid + i * TPB;
            if (idx < WL_F4) wl4[idx] = wp4[idx];
        }
    }

    float4 hv  = make_float4(0.f, 0.f, 0.f, 0.f);
    float4 cxv = make_float4(0.f, 0.f, 0.f, 0.f);
    if (wvu == 1) hv  = ((const float4*)hx)[row];
    else          cxv = ((const float4*)cx)[row];

    __syncthreads();   // weights visible

    // This wave's half of x: 32 float4 per row (one 128 B line per stage/row).
    const float4* xr    = (const float4*)x + (size_t)row * 64 + wvu * 32;
    const float4* wbase = wl4 + wvu * 512;   // this wave's 4 stages x 128 float4

    float acc[16];
#pragma unroll
    for (int j = 0; j < 16; ++j) acc[j] = 0.0f;

    // Register double buffer (r4-proven: no spill, compiler inserts precise
    // counted vmcnt so next stage's loads fly under current stage's FMAs).
    float4 A[8], B[8];
#pragma unroll
    for (int u = 0; u < 8; ++u) A[u] = xr[u];          // stage 0
#pragma unroll
    for (int u = 0; u < 8; ++u) B[u] = xr[8 + u];      // stage 1
    consume8(A, wbase + 0 * 128, acc);
#pragma unroll
    for (int u = 0; u < 8; ++u) A[u] = xr[16 + u];     // stage 2
    consume8(B, wbase + 1 * 128, acc);
#pragma unroll
    for (int u = 0; u < 8; ++u) B[u] = xr[24 + u];     // stage 3
    consume8(A, wbase + 2 * 128, acc);
    consume8(B, wbase + 3 * 128, acc);

    if (wvu == 1) {
        // Tail: k = 256..259 from hx[row][0..3]; weights at float4 idx 1024+.
        const float4* wt = wl4 + 1024;
#pragma unroll
        for (int m = 0; m < 4; ++m) {
            float he = (m == 0) ? hv.x : (m == 1) ? hv.y : (m == 2) ? hv.z : hv.w;
            float4 w0 = wt[m * 4 + 0], w1 = wt[m * 4 + 1];
            float4 w2 = wt[m * 4 + 2], w3 = wt[m * 4 + 3];
            acc[ 0] = fmaf(he, w0.x, acc[ 0]); acc[ 1] = fmaf(he, w0.y, acc[ 1]);
            acc[ 2] = fmaf(he, w0.z, acc[ 2]); acc[ 3] = fmaf(he, w0.w, acc[ 3]);
            acc[ 4] = fmaf(he, w1.x, acc[ 4]); acc[ 5] = fmaf(he, w1.y, acc[ 5]);
            acc[ 6] = fmaf(he, w1.z, acc[ 6]); acc[ 7] = fmaf(he, w1.w, acc[ 7]);
            acc[ 8] = fmaf(he, w2.x, acc[ 8]); acc[ 9] = fmaf(he, w2.y, acc[ 9]);
            acc[10] = fmaf(he, w2.z, acc[10]); acc[11] = fmaf(he, w2.w, acc[11]);
            acc[12] = fmaf(he, w3.x, acc[12]); acc[13] = fmaf(he, w3.y, acc[13]);
            acc[14] = fmaf(he, w3.z, acc[14]); acc[15] = fmaf(he, w3.w, acc[15]);
        }
    }

    __syncthreads();   // all weight reads done -> first 4 KB reusable
    float4* accx4 = wl4;  // union: exchange buffer
    if (wvu == 1) {
#pragma unroll
        for (int j4 = 0; j4 < 4; ++j4)
            accx4[lane * 4 + j4] = make_float4(acc[j4 * 4 + 0], acc[j4 * 4 + 1],
                                               acc[j4 * 4 + 2], acc[j4 * 4 + 3]);
    }
    __syncthreads();

    if (wvu == 0) {
#pragma unroll
        for (int j4 = 0; j4 < 4; ++j4) {
            float4 p = accx4[lane * 4 + j4];
            acc[j4 * 4 + 0] += p.x; acc[j4 * 4 + 1] += p.y;
            acc[j4 * 4 + 2] += p.z; acc[j4 * 4 + 3] += p.w;
        }

        // ---- Quantum gate closed form ----
        // c_w = cos(angle_w + b_w + th_w); E0=c1*c2*c3, E1=c0*c1, E2=c0*c1*c2, E3=c0*c1*c2*c3
        const float* bthl = (const float*)wl4 + 4160;  // beyond the 4 KB accx region
        float co[16];
#pragma unroll
        for (int j = 0; j < 16; ++j) co[j] = __cosf(acc[j] + bthl[j]);

        float G[16];
#pragma unroll
        for (int g = 0; g < 4; ++g) {
            float c0 = co[g * 4 + 0], c1 = co[g * 4 + 1];
            float c2 = co[g * 4 + 2], c3 = co[g * 4 + 3];
            float e1 = c0 * c1;
            float e2 = e1 * c2;
            float e3 = e2 * c3;
            float e0 = c1 * c2 * c3;
            G[g * 4 + 0] = e0; G[g * 4 + 1] = e1; G[g * 4 + 2] = e2; G[g * 4 + 3] = e3;
        }

        float cxa[4] = {cxv.x, cxv.y, cxv.z, cxv.w};
        float hn[4], cn[4];
#pragma unroll
        for (int w = 0; w < 4; ++w) {
            float fg = sigm_(G[0 * 4 + w]);
            float ig = sigm_(G[1 * 4 + w]);
            float ug = tanh_(G[2 * 4 + w]);
            float og = sigm_(G[3 * 4 + w]);
            float c_ = fg * cxa[w] + ig * ug;
            cn[w] = c_;
            hn[w] = og * tanh_(c_);
        }

        ((float4*)out)[row]      = make_float4(hn[0], hn[1], hn[2], hn[3]);  // h_new
        ((float4*)out)[NB + row] = make_float4(cn[0], cn[1], cn[2], cn[3]);  // c_new
    }
}

extern "C" void kernel_launch(void* const* d_in, const int* in_sizes, int n_in,
                              void* d_out, int out_size, void* d_ws, size_t ws_size,
                              hipStream_t stream) {
    const float* x   = (const float*)d_in[0];
    const float* hx  = (const float*)d_in[1];
    const float* cx  = (const float*)d_in[2];
    const float* Wf  = (const float*)d_in[3];
    const float* bf  = (const float*)d_in[4];
    const float* Wi  = (const float*)d_in[5];
    const float* bi  = (const float*)d_in[6];
    const float* Wu  = (const float*)d_in[7];
    const float* bu  = (const float*)d_in[8];
    const float* Wo  = (const float*)d_in[9];
    const float* bo  = (const float*)d_in[10];
    const float* thf = (const float*)d_in[11];
    const float* thi = (const float*)d_in[12];
    const float* thu = (const float*)d_in[13];
    const float* tho = (const float*)d_in[14];

    float* Wp  = (float*)d_ws;            // 260*16 floats, bth contiguous after
    float* bth = Wp + FANIN * 16;         // 16 floats

    qlstm_prep<<<(FANIN * 16 + 255) / 256, 256, 0, stream>>>(
        Wf, bf, Wi, bi, Wu, bu, Wo, bo, thf, thi, thu, tho, Wp, bth);

    qlstm_main<<<NB / 64, TPB, 0, stream>>>(
        x, hx, cx, Wp, bth, (float*)d_out);
}

// Round 6
// 223.479 us; speedup vs baseline: 1.0942x; 1.0942x over previous
//
#include <hip/hip_runtime.h>

#define NB    131072   // batch rows
#define TPB   256      // 4 waves/block: wave w owns k in [w*64, w*64+64); wave3 + hx tail
#define FANIN 260

__device__ __forceinline__ float sigm_(float x) { return 1.0f / (1.0f + __expf(-x)); }
__device__ __forceinline__ float tanh_(float x) { return 1.0f - 2.0f / (__expf(2.0f * x) + 1.0f); }

// Repack the four [4,260] weight matrices into k-major Wp[k][16] (gw = g*4+w)
// and fuse bias+theta into bth[16]. ws re-poison is UNCONDITIONAL (measured r1),
// so using the workspace costs nothing.
__global__ void qlstm_prep(const float* __restrict__ Wf, const float* __restrict__ bf,
                           const float* __restrict__ Wi, const float* __restrict__ bi,
                           const float* __restrict__ Wu, const float* __restrict__ bu,
                           const float* __restrict__ Wo, const float* __restrict__ bo,
                           const float* __restrict__ thf, const float* __restrict__ thi,
                           const float* __restrict__ thu, const float* __restrict__ tho,
                           float* __restrict__ Wp, float* __restrict__ bth) {
    int t = blockIdx.x * blockDim.x + threadIdx.x;
    if (t < FANIN * 16) {
        int k = t >> 4, gw = t & 15, g = gw >> 2, w = gw & 3;
        const float* Wg = (g == 0) ? Wf : (g == 1) ? Wi : (g == 2) ? Wu : Wo;
        Wp[t] = Wg[w * FANIN + k];
    }
    if (t < 16) {
        int g = t >> 2, w = t & 3;
        const float* bg = (g == 0) ? bf  : (g == 1) ? bi  : (g == 2) ? bu  : bo;
        const float* tg = (g == 0) ? thf : (g == 1) ? thi : (g == 2) ? thu : tho;
        bth[t] = bg[w] + tg[w];
    }
}

__global__ __launch_bounds__(TPB, 4) void qlstm_main(
        const float* __restrict__ x, const float* __restrict__ hx,
        const float* __restrict__ cx, const float* __restrict__ Wp,
        const float* __restrict__ bth, float* __restrict__ out) {
    // Transposed partial-acc exchange: accx[j][srcwave][lane] -> per-j writes are
    // lane-consecutive dwords (conflict-free b32). 16*3*64*4 = 12 KB.
    __shared__ float accx[16 * 3 * 64];

    const int tid  = threadIdx.x;
    const int lane = tid & 63;
    const int wv   = tid >> 6;
    const int wvu  = __builtin_amdgcn_readfirstlane(wv);   // SGPR wave id
    const int row0 = blockIdx.x * 64;
    const int row  = row0 + lane;

    // This wave's k-quarter of its own row: 16 float4 = 256 B = 2 cache lines.
    const float4* xr = (const float4*)x + (size_t)row * 64 + wvu * 16;

    // MAX MLP: issue ALL 16 divergent loads up front (64 VGPR held).
    // Consume order matches issue order -> compiler emits counted vmcnt(15..0)
    // waits; ~1024 cache lines per wave in flight from cycle 0.
    float4 xb[16];
#pragma unroll
    for (int u = 0; u < 16; ++u) xb[u] = xr[u];

    float4 hv  = make_float4(0.f, 0.f, 0.f, 0.f);
    float4 cxv = make_float4(0.f, 0.f, 0.f, 0.f);
    if (wvu == 3) hv  = ((const float4*)hx)[row];   // tail owner
    if (wvu == 0) cxv = ((const float4*)cx)[row];   // epilogue owner

    float acc[16];
#pragma unroll
    for (int j = 0; j < 16; ++j) acc[j] = 0.0f;

    // Weights: wave-uniform address -> s_load stream, 4 KB per wave (scalar
    // pipe; r4 measured this path strictly better than LDS broadcast).
    const float* wbase = Wp + wvu * 64 * 16;
#pragma unroll
    for (int c4 = 0; c4 < 16; ++c4) {
#pragma unroll
        for (int m = 0; m < 4; ++m) {
            float xe = (m == 0) ? xb[c4].x : (m == 1) ? xb[c4].y
                     : (m == 2) ? xb[c4].z : xb[c4].w;
            const float* wp = wbase + (c4 * 4 + m) * 16;
#pragma unroll
            for (int j = 0; j < 16; ++j) acc[j] = fmaf(xe, wp[j], acc[j]);
        }
    }

    if (wvu == 3) {
        // Tail: k = 256..259 from hx[row][0..3].
        const float* wp = Wp + 256 * 16;
#pragma unroll
        for (int j = 0; j < 16; ++j) acc[j] = fmaf(hv.x, wp[j],      acc[j]);
#pragma unroll
        for (int j = 0; j < 16; ++j) acc[j] = fmaf(hv.y, wp[16 + j], acc[j]);
#pragma unroll
        for (int j = 0; j < 16; ++j) acc[j] = fmaf(hv.z, wp[32 + j], acc[j]);
#pragma unroll
        for (int j = 0; j < 16; ++j) acc[j] = fmaf(hv.w, wp[48 + j], acc[j]);
    }

    // Publish partials from waves 1..3 (transposed: conflict-free b32 writes).
    if (wvu != 0) {
#pragma unroll
        for (int j = 0; j < 16; ++j)
            accx[(j * 3 + (wvu - 1)) * 64 + lane] = acc[j];
    }
    __syncthreads();

    if (wvu == 0) {
#pragma unroll
        for (int j = 0; j < 16; ++j)
            acc[j] += accx[(j * 3 + 0) * 64 + lane]
                    + accx[(j * 3 + 1) * 64 + lane]
                    + accx[(j * 3 + 2) * 64 + lane];

        // ---- Quantum gate closed form ----
        // c_w = cos(angle_w + b_w + th_w); E0=c1*c2*c3, E1=c0*c1, E2=c0*c1*c2, E3=c0*c1*c2*c3
        float co[16];
#pragma unroll
        for (int j = 0; j < 16; ++j) co[j] = __cosf(acc[j] + bth[j]);

        float G[16];
#pragma unroll
        for (int g = 0; g < 4; ++g) {
            float c0 = co[g * 4 + 0], c1 = co[g * 4 + 1];
            float c2 = co[g * 4 + 2], c3 = co[g * 4 + 3];
            float e1 = c0 * c1;
            float e2 = e1 * c2;
            float e3 = e2 * c3;
            float e0 = c1 * c2 * c3;
            G[g * 4 + 0] = e0; G[g * 4 + 1] = e1; G[g * 4 + 2] = e2; G[g * 4 + 3] = e3;
        }

        float cxa[4] = {cxv.x, cxv.y, cxv.z, cxv.w};
        float hn[4], cn[4];
#pragma unroll
        for (int w = 0; w < 4; ++w) {
            float fg = sigm_(G[0 * 4 + w]);
            float ig = sigm_(G[1 * 4 + w]);
            float ug = tanh_(G[2 * 4 + w]);
            float og = sigm_(G[3 * 4 + w]);
            float c_ = fg * cxa[w] + ig * ug;
            cn[w] = c_;
            hn[w] = og * tanh_(c_);
        }

        ((float4*)out)[row]      = make_float4(hn[0], hn[1], hn[2], hn[3]);  // h_new
        ((float4*)out)[NB + row] = make_float4(cn[0], cn[1], cn[2], cn[3]);  // c_new
    }
}

extern "C" void kernel_launch(void* const* d_in, const int* in_sizes, int n_in,
                              void* d_out, int out_size, void* d_ws, size_t ws_size,
                              hipStream_t stream) {
    const float* x   = (const float*)d_in[0];
    const float* hx  = (const float*)d_in[1];
    const float* cx  = (const float*)d_in[2];
    const float* Wf  = (const float*)d_in[3];
    const float* bf  = (const float*)d_in[4];
    const float* Wi  = (const float*)d_in[5];
    const float* bi  = (const float*)d_in[6];
    const float* Wu  = (const float*)d_in[7];
    const float* bu  = (const float*)d_in[8];
    const float* Wo  = (const float*)d_in[9];
    const float* bo  = (const float*)d_in[10];
    const float* thf = (const float*)d_in[11];
    const float* thi = (const float*)d_in[12];
    const float* thu = (const float*)d_in[13];
    const float* tho = (const float*)d_in[14];

    float* Wp  = (float*)d_ws;            // 260*16 floats
    float* bth = Wp + FANIN * 16;         // 16 floats

    qlstm_prep<<<(FANIN * 16 + 255) / 256, 256, 0, stream>>>(
        Wf, bf, Wi, bi, Wu, bu, Wo, bo, thf, thi, thu, tho, Wp, bth);

    qlstm_main<<<NB / 64, TPB, 0, stream>>>(
        x, hx, cx, Wp, bth, (float*)d_out);
}